// Round 5
// baseline (1678.498 us; speedup 1.0000x reference)
//
#include <hip/hip_runtime.h>
#include <hip/hip_bf16.h>
#include <math.h>

#define B_ROWS   32768
#define NSTEPS   5
#define EPS_BN   1e-5f
#define RELAX_C  1.5f
#define SQRT_HALF 0.70710678118654752440f

typedef _Float16 f16;
typedef _Float16 f16x4 __attribute__((ext_vector_type(4)));
typedef _Float16 f16x8 __attribute__((ext_vector_type(8)));
typedef float    f32x4 __attribute__((ext_vector_type(4)));

// GLU pairing permutation: permuted col c -> source col.
// Within each 32-col group g: positions 0..15 = y0 (src g*16+o), 16..31 = gate (src g*16+(o-16)+256).
__device__ __forceinline__ int glu_perm2(int c) {
    int g = c >> 5, o = c & 31;
    return (o < 16) ? (g * 16 + o) : (g * 16 + (o - 16) + 256);
}

// ---------------- prep kernels ----------------
__global__ void prep_bn_kernel(
    const float* __restrict__ bn0_g, const float* __restrict__ bn0_b,
    const float* __restrict__ bn0_m, const float* __restrict__ bn0_v,
    const float* __restrict__ ft_g, const float* __restrict__ ft_b,
    const float* __restrict__ ft_m, const float* __restrict__ ft_v,
    const float* __restrict__ att_g, const float* __restrict__ att_b,
    const float* __restrict__ att_m, const float* __restrict__ att_v,
    float* __restrict__ sc0, float* __restrict__ sh0,
    float* __restrict__ ftS, float* __restrict__ ftH,
    float* __restrict__ attS, float* __restrict__ attH)
{
    int idx = blockIdx.x * blockDim.x + threadIdx.x;
    if (idx < 512) {
        float s = bn0_g[idx] * rsqrtf(bn0_v[idx] + EPS_BN);
        sc0[idx] = s;
        sh0[idx] = bn0_b[idx] - bn0_m[idx] * s;
    } else if (idx < 512 + 24 * 512) {
        int q = idx - 512;
        int tb = q >> 9;
        int c = q & 511;
        int src = tb * 512 + glu_perm2(c);
        float s = ft_g[src] * rsqrtf(ft_v[src] + EPS_BN);
        ftS[q] = s;
        ftH[q] = ft_b[src] - ft_m[src] * s;
    } else if (idx < 512 + 24 * 512 + 5 * 512) {
        int q = idx - 512 - 24 * 512;
        float s = att_g[q] * rsqrtf(att_v[q] + EPS_BN);
        attS[q] = s;
        attH[q] = att_b[q] - att_m[q] * s;
    }
}

// Weight prep (batched over grid.y): src [K][512] fp32 -> dst [512][K] f16 (transposed), optional GLU col-perm
__global__ void wprep_kernel(const float* __restrict__ src,
                             f16* __restrict__ dst, int K, int doperm)
{
    const int mat = blockIdx.y;
    src += (size_t)mat * K * 512;
    dst += (size_t)mat * 512 * K;
    int i = blockIdx.x * blockDim.x + threadIdx.x;
    if (i >= 512 * K) return;
    int n = i / K, k = i - n * K;
    int sn = doperm ? glu_perm2(n) : n;
    dst[i] = (f16)src[(size_t)k * 512 + sn];
}

// feats = bn0(features) -> f16; prior = 1 (fp32)
__global__ void bn0_split_kernel(const float* __restrict__ x,
                                 const float* __restrict__ sc,
                                 const float* __restrict__ sh,
                                 f16* __restrict__ fh,
                                 float* __restrict__ prior)
{
    int i = blockIdx.x * blockDim.x + threadIdx.x;   // over B*512/4
    int base = i * 4;
    int c = base & 511;
    float4 xv = *(const float4*)(x + base);
    f16x4 hv;
    hv.x = (f16)(xv.x * sc[c]     + sh[c]);
    hv.y = (f16)(xv.y * sc[c + 1] + sh[c + 1]);
    hv.z = (f16)(xv.z * sc[c + 2] + sh[c + 2]);
    hv.w = (f16)(xv.w * sc[c + 3] + sh[c + 3]);
    *(f16x4*)(fh + base) = hv;
    *(float4*)(prior + base) = make_float4(1.f, 1.f, 1.f, 1.f);
}

__global__ void zero_kernel(float4* __restrict__ p, int n4)
{
    int i = blockIdx.x * blockDim.x + threadIdx.x;
    if (i < n4) p[i] = make_float4(0.f, 0.f, 0.f, 0.f);
}

// ---------------- direct-load fp16 MFMA GEMM + fused epilogue (dense) ----------------
// No LDS, no barriers: each wave loads its MFMA fragments straight from L2-resident
// operands (B <= 512KB, A panel L2-cached within XCD). 128x128 block tile, 4 waves
// each 64x64, 2-deep register ping-pong prefetch over BK=32.
// MODE 0: out = glu(bn(A@W)); MODE 1: + res*sqrt(.5); MODE 2: MODE1 + oacc += relu (oc<128)
template<int MODE>
__global__ __launch_bounds__(256, 3) void gemm_direct(
    const f16* __restrict__ A, int ldA, int K,
    const f16* __restrict__ B,               // [512][K] f16, GLU-permuted rows
    const float* __restrict__ scale, const float* __restrict__ shift,
    const f16* __restrict__ res,
    f16* __restrict__ out,
    float* __restrict__ oacc)
{
    const int tid  = threadIdx.x;
    const int lane = tid & 63;
    const int w    = tid >> 6;
    const int wm   = w >> 1, wn = w & 1;
    // XCD-bijective swizzle; 4 col-blocks of a row-panel adjacent within an XCD chunk
    const int d    = blockIdx.x;
    const int bid  = (d & 7) * (gridDim.x >> 3) + (d >> 3);
    const int by   = bid >> 2, bx = bid & 3;
    const int brow = by * 128 + wm * 64;
    const int bcol = bx * 128 + wn * 64;
    const int lr   = lane & 15;
    const int lk   = (lane >> 4) * 8;

    const f16* pa = A + (size_t)(brow + lr) * ldA + lk;
    const f16* pb = B + (size_t)(bcol + lr) * K + lk;
    const size_t sa = (size_t)16 * ldA;
    const size_t sb = (size_t)16 * K;

    f32x4 acc[4][4];
    #pragma unroll
    for (int m = 0; m < 4; ++m)
        #pragma unroll
        for (int n = 0; n < 4; ++n)
            acc[m][n] = f32x4{0.f, 0.f, 0.f, 0.f};

    f16x8 aA[4], bA[4], aB[4], bB[4];
    #pragma unroll
    for (int m = 0; m < 4; ++m) aA[m] = *(const f16x8*)(pa + m * sa);
    #pragma unroll
    for (int n = 0; n < 4; ++n) bA[n] = *(const f16x8*)(pb + n * sb);

    const int NT = K >> 5;                    // 8 or 16 (even)
    for (int t = 0; t < NT; t += 2) {
        // prefetch step t+1 (always valid: NT even)
        #pragma unroll
        for (int m = 0; m < 4; ++m) aB[m] = *(const f16x8*)(pa + m * sa + (t + 1) * 32);
        #pragma unroll
        for (int n = 0; n < 4; ++n) bB[n] = *(const f16x8*)(pb + n * sb + (t + 1) * 32);
        #pragma unroll
        for (int n = 0; n < 4; ++n)
            #pragma unroll
            for (int m = 0; m < 4; ++m)
                acc[m][n] = __builtin_amdgcn_mfma_f32_16x16x32_f16(aA[m], bA[n], acc[m][n], 0, 0, 0);
        if (t + 2 < NT) {
            #pragma unroll
            for (int m = 0; m < 4; ++m) aA[m] = *(const f16x8*)(pa + m * sa + (t + 2) * 32);
            #pragma unroll
            for (int n = 0; n < 4; ++n) bA[n] = *(const f16x8*)(pb + n * sb + (t + 2) * 32);
        }
        #pragma unroll
        for (int n = 0; n < 4; ++n)
            #pragma unroll
            for (int m = 0; m < 4; ++m)
                acc[m][n] = __builtin_amdgcn_mfma_f32_16x16x32_f16(aB[m], bB[n], acc[m][n], 0, 0, 0);
    }

    // epilogue: fragment row' = (lane>>4)*4+r, col' = lane&15; GLU pairs in-lane via permuted W
    #pragma unroll
    for (int p = 0; p < 2; ++p) {
        const int cb = bcol + p * 32;                 // 32-col GLU group base
        const float sA = scale[cb + lr],      hA = shift[cb + lr];
        const float sB = scale[cb + 16 + lr], hB = shift[cb + 16 + lr];
        const int oc = (cb >> 1) + lr;
        #pragma unroll
        for (int m = 0; m < 4; ++m) {
            const int row0 = brow + m * 16 + (lane >> 4) * 4;
            #pragma unroll
            for (int r = 0; r < 4; ++r) {
                const int row = row0 + r;
                float y0 = acc[m][2 * p][r]     * sA + hA;
                float y1 = acc[m][2 * p + 1][r] * sB + hB;
                float val = y0 / (1.f + expf(-y1));
                const size_t oi = (size_t)row * 256 + oc;
                if constexpr (MODE >= 1)
                    val += SQRT_HALF * (float)res[oi];
                out[oi] = (f16)val;
                if constexpr (MODE == 2) {
                    if (oc < 128) oacc[(size_t)row * 128 + oc] += fmaxf(val, 0.f);
                }
            }
        }
    }
}

// ---------------- fused attention GEMM + sparsemax (Newton) + mf emission ----------------
// Block: 32 rows x 512 cols, 4 waves. GEMM direct-load (K=128), bn'd att -> LDS f32.
// Phase 2: z = att*prior; Newton solve tau (exact, ~4-6 iters); write mask (d_out),
// prior *= (1.5-mask); mf = mask*feats (dense f16) for the next transformer's G1.
__global__ __launch_bounds__(256, 2) void att_sparsemax_kernel(
    const f16* __restrict__ A, int ldA,      // x[:,128:256]
    const f16* __restrict__ Bw,              // [512][128] f16
    const float* __restrict__ scale, const float* __restrict__ shift,
    const f16* __restrict__ feats,
    float* __restrict__ prior,
    float* __restrict__ mask_out,
    f16* __restrict__ mf)
{
    __shared__ float attLds[32 * 512];
    const int tid  = threadIdx.x;
    const int lane = tid & 63;
    const int w    = tid >> 6;
    const int brow = blockIdx.x * 32;
    const int lr   = lane & 15;
    const int lk   = (lane >> 4) * 8;

    // GEMM: wave w computes cols w*128..+127 for all 32 rows; K=128, NT=4
    f32x4 acc[2][8];
    #pragma unroll
    for (int m = 0; m < 2; ++m)
        #pragma unroll
        for (int n = 0; n < 8; ++n)
            acc[m][n] = f32x4{0.f, 0.f, 0.f, 0.f};

    const f16* pa = A + (size_t)(brow + lr) * ldA + lk;
    const f16* pb = Bw + (size_t)(w * 128 + lr) * 128 + lk;

    f16x8 a0[2], b0[8], a1[2], b1[8];
    #pragma unroll
    for (int m = 0; m < 2; ++m) a0[m] = *(const f16x8*)(pa + m * 16 * ldA);
    #pragma unroll
    for (int n = 0; n < 8; ++n) b0[n] = *(const f16x8*)(pb + n * 16 * 128);

    #pragma unroll
    for (int t = 0; t < 4; t += 2) {
        #pragma unroll
        for (int m = 0; m < 2; ++m) a1[m] = *(const f16x8*)(pa + m * 16 * ldA + (t + 1) * 32);
        #pragma unroll
        for (int n = 0; n < 8; ++n) b1[n] = *(const f16x8*)(pb + n * 16 * 128 + (t + 1) * 32);
        #pragma unroll
        for (int n = 0; n < 8; ++n)
            #pragma unroll
            for (int m = 0; m < 2; ++m)
                acc[m][n] = __builtin_amdgcn_mfma_f32_16x16x32_f16(a0[m], b0[n], acc[m][n], 0, 0, 0);
        if (t + 2 < 4) {
            #pragma unroll
            for (int m = 0; m < 2; ++m) a0[m] = *(const f16x8*)(pa + m * 16 * ldA + (t + 2) * 32);
            #pragma unroll
            for (int n = 0; n < 8; ++n) b0[n] = *(const f16x8*)(pb + n * 16 * 128 + (t + 2) * 32);
        }
        #pragma unroll
        for (int n = 0; n < 8; ++n)
            #pragma unroll
            for (int m = 0; m < 2; ++m)
                acc[m][n] = __builtin_amdgcn_mfma_f32_16x16x32_f16(a1[m], b1[n], acc[m][n], 0, 0, 0);
    }

    // bn'd att -> LDS
    #pragma unroll
    for (int m = 0; m < 2; ++m) {
        const int r0 = m * 16 + (lane >> 4) * 4;
        #pragma unroll
        for (int n = 0; n < 8; ++n) {
            const int col = w * 128 + n * 16 + lr;
            const float s = scale[col], h = shift[col];
            #pragma unroll
            for (int r = 0; r < 4; ++r)
                attLds[(r0 + r) * 512 + col] = acc[m][n][r] * s + h;
        }
    }
    __syncthreads();

    // phase 2: wave w handles rows w*8 .. w*8+7
    for (int rr = 0; rr < 8; ++rr) {
        const int row = w * 8 + rr;
        const int grow = brow + row;
        const size_t gbase = (size_t)grow * 512 + lane;

        float z[8], pr[8];
        #pragma unroll
        for (int j = 0; j < 8; ++j) {
            pr[j] = prior[gbase + j * 64];
            z[j] = attLds[row * 512 + lane + j * 64] * pr[j];
        }
        float mx = z[0];
        #pragma unroll
        for (int j = 1; j < 8; ++j) mx = fmaxf(mx, z[j]);
        #pragma unroll
        for (int off = 32; off; off >>= 1) mx = fmaxf(mx, __shfl_xor(mx, off));

        // Newton on f(tau) = sum(z-tau)+ - 1 : piecewise-linear, convex, monotone
        // from tau0 = mx-1 (f>=0); converges exactly once support stabilizes.
        float tau = mx - 1.0f;
        for (int it = 0; it < 20; ++it) {
            float s = 0.f, c = 0.f;
            #pragma unroll
            for (int j = 0; j < 8; ++j) {
                float dz = z[j] - tau;
                if (dz > 0.f) { s += dz; c += 1.f; }
            }
            #pragma unroll
            for (int off = 32; off; off >>= 1) {
                s += __shfl_xor(s, off);
                c += __shfl_xor(c, off);
            }
            float tn = tau + (s - 1.0f) / c;
            if (!(tn > tau)) break;    // wave-uniform: converged
            tau = tn;
        }

        #pragma unroll
        for (int j = 0; j < 8; ++j) {
            const size_t ix = gbase + j * 64;
            float m = fmaxf(z[j] - tau, 0.f);
            mask_out[ix] = m;
            prior[ix] = pr[j] * (RELAX_C - m);
            mf[ix] = (f16)(m * (float)feats[ix]);
        }
    }
}

// ---------------- final fp32 SIMT GEMM (K=128, N=128) ----------------
__global__ __launch_bounds__(256) void gemm_f32_final(
    const float* __restrict__ A,
    const float* __restrict__ W,
    const float* __restrict__ bias,
    float* __restrict__ out)
{
    __shared__ float As[16][128];
    __shared__ float Bs[16][128];
    const int tid = threadIdx.x;
    const int tm = tid >> 4, tn = tid & 15;
    const int brow = blockIdx.x * 128;
    float acc[8][8] = {};
    for (int k0 = 0; k0 < 128; k0 += 16) {
        #pragma unroll
        for (int i = 0; i < 2; ++i) {
            int f = tid + i * 256;
            int row = f >> 2, kq = (f & 3) << 2;
            float4 av = *(const float4*)(A + (size_t)(brow + row) * 128 + k0 + kq);
            As[kq + 0][row] = av.x;
            As[kq + 1][row] = av.y;
            As[kq + 2][row] = av.z;
            As[kq + 3][row] = av.w;
            int kr = f >> 5, nq = (f & 31) << 2;
            *(float4*)(&Bs[kr][nq]) = *(const float4*)(W + (size_t)(k0 + kr) * 128 + nq);
        }
        __syncthreads();
        #pragma unroll
        for (int kk = 0; kk < 16; ++kk) {
            float a[8], b[8];
            *(float4*)(a)     = *(const float4*)(&As[kk][tm * 8]);
            *(float4*)(a + 4) = *(const float4*)(&As[kk][tm * 8 + 4]);
            *(float4*)(b)     = *(const float4*)(&Bs[kk][tn * 8]);
            *(float4*)(b + 4) = *(const float4*)(&Bs[kk][tn * 8 + 4]);
            #pragma unroll
            for (int i = 0; i < 8; ++i)
                #pragma unroll
                for (int j = 0; j < 8; ++j)
                    acc[i][j] += a[i] * b[j];
        }
        __syncthreads();
    }
    #pragma unroll
    for (int i = 0; i < 8; ++i) {
        int row = brow + tm * 8 + i;
        #pragma unroll
        for (int j = 0; j < 8; ++j)
            out[(size_t)row * 128 + tn * 8 + j] = acc[i][j] + bias[tn * 8 + j];
    }
}

// ---------------- launch ----------------
extern "C" void kernel_launch(void* const* d_in, const int* in_sizes, int n_in,
                              void* d_out, int out_size, void* d_ws, size_t ws_size,
                              hipStream_t stream)
{
    const float* features = (const float*)d_in[0];
    const float* bn0_g = (const float*)d_in[1];
    const float* bn0_b = (const float*)d_in[2];
    const float* bn0_m = (const float*)d_in[3];
    const float* bn0_v = (const float*)d_in[4];
    const float* Ws0   = (const float*)d_in[5];
    const float* Ws1   = (const float*)d_in[6];
    const float* Wu    = (const float*)d_in[7];
    const float* ft_g  = (const float*)d_in[8];
    const float* ft_b  = (const float*)d_in[9];
    const float* ft_m  = (const float*)d_in[10];
    const float* ft_v  = (const float*)d_in[11];
    const float* W_att = (const float*)d_in[12];
    const float* att_g = (const float*)d_in[13];
    const float* att_b = (const float*)d_in[14];
    const float* att_m = (const float*)d_in[15];
    const float* att_v = (const float*)d_in[16];
    const float* Wf    = (const float*)d_in[17];
    const float* bf    = (const float*)d_in[18];
    float* out = (float*)d_out;

    // ---- ws layout (bytes) ----
    char* wp = (char*)d_ws;
    auto alloc = [&](size_t bytes) { char* r = wp; wp += (bytes + 255) & ~(size_t)255; return r; };
    const size_t BR = B_ROWS;
    f16* feats  = (f16*)alloc(BR * 512 * 2);
    f16* mfbuf  = (f16*)alloc(BR * 512 * 2);
    f16* ubuf   = (f16*)alloc(BR * 256 * 2);
    f16* vbuf   = (f16*)alloc(BR * 256 * 2);
    float* prior = (float*)alloc(BR * 512 * 4);
    float* oacc  = (float*)alloc(BR * 128 * 4);
    f16* ws0  = (f16*)alloc(512 * 512 * 2);
    f16* ws1  = (f16*)alloc(512 * 256 * 2);
    f16* wu   = (f16*)alloc((size_t)12 * 512 * 256 * 2);
    f16* wat  = (f16*)alloc((size_t)5 * 512 * 128 * 2);
    float* ftS  = (float*)alloc(24 * 512 * 4);
    float* ftH  = (float*)alloc(24 * 512 * 4);
    float* attS = (float*)alloc(5 * 512 * 4);
    float* attH = (float*)alloc(5 * 512 * 4);
    float* sc0  = (float*)alloc(512 * 4);
    float* sh0  = (float*)alloc(512 * 4);

    // ---- prep ----
    prep_bn_kernel<<<60, 256, 0, stream>>>(
        bn0_g, bn0_b, bn0_m, bn0_v, ft_g, ft_b, ft_m, ft_v,
        att_g, att_b, att_m, att_v, sc0, sh0, ftS, ftH, attS, attH);
    wprep_kernel<<<dim3(512 * 512 / 256, 1), 256, 0, stream>>>(Ws0, ws0, 512, 1);
    wprep_kernel<<<dim3(512 * 256 / 256, 1), 256, 0, stream>>>(Ws1, ws1, 256, 1);
    wprep_kernel<<<dim3(512 * 256 / 256, 12), 256, 0, stream>>>(Wu, wu, 256, 1);
    wprep_kernel<<<dim3(512 * 128 / 256, 5), 256, 0, stream>>>(W_att, wat, 128, 0);
    bn0_split_kernel<<<(B_ROWS * 512 / 4) / 256, 256, 0, stream>>>(
        features, sc0, sh0, feats, prior);
    zero_kernel<<<(B_ROWS * 128 / 4) / 256, 256, 0, stream>>>((float4*)oacc, B_ROWS * 128 / 4);

    const int grid = 4 * (B_ROWS / 128);   // 1024 blocks, swizzled in-kernel

    // transformer t: G1 (K=512) + G2..G4 (K=256)
    auto ft = [&](const f16* in, int t, bool accum) {
        const f16* wu0 = wu + (size_t)(t * 2 + 0) * 131072;
        const f16* wu1 = wu + (size_t)(t * 2 + 1) * 131072;
        gemm_direct<0><<<grid, 256, 0, stream>>>(in, 512, 512, ws0,
            ftS + (t * 4 + 0) * 512, ftH + (t * 4 + 0) * 512,
            nullptr, ubuf, nullptr);
        gemm_direct<1><<<grid, 256, 0, stream>>>(ubuf, 256, 256, ws1,
            ftS + (t * 4 + 1) * 512, ftH + (t * 4 + 1) * 512,
            ubuf, vbuf, nullptr);
        gemm_direct<1><<<grid, 256, 0, stream>>>(vbuf, 256, 256, wu0,
            ftS + (t * 4 + 2) * 512, ftH + (t * 4 + 2) * 512,
            vbuf, ubuf, nullptr);
        if (accum)
            gemm_direct<2><<<grid, 256, 0, stream>>>(ubuf, 256, 256, wu1,
                ftS + (t * 4 + 3) * 512, ftH + (t * 4 + 3) * 512,
                ubuf, vbuf, oacc);
        else
            gemm_direct<1><<<grid, 256, 0, stream>>>(ubuf, 256, 256, wu1,
                ftS + (t * 4 + 3) * 512, ftH + (t * 4 + 3) * 512,
                ubuf, vbuf, nullptr);
    };

    ft(feats, 0, false);

    for (int s = 0; s < NSTEPS; ++s) {
        float* mask_s = out + 4194304 + (size_t)s * 16777216;
        att_sparsemax_kernel<<<B_ROWS / 32, 256, 0, stream>>>(
            vbuf + 128, 256, wat + (size_t)s * 65536,
            attS + s * 512, attH + s * 512,
            feats, prior, mask_s, mfbuf);
        ft(mfbuf, s + 1, true);
    }

    gemm_f32_final<<<B_ROWS / 128, 256, 0, stream>>>(oacc, Wf, bf, out);
}

// Round 6
// 1235.747 us; speedup vs baseline: 1.3583x; 1.3583x over previous
//
#include <hip/hip_runtime.h>
#include <hip/hip_bf16.h>
#include <math.h>

#define B_ROWS   32768
#define NSTEPS   5
#define EPS_BN   1e-5f
#define RELAX_C  1.5f
#define SQRT_HALF 0.70710678118654752440f

typedef _Float16 f16;
typedef _Float16 f16x4 __attribute__((ext_vector_type(4)));
typedef _Float16 f16x8 __attribute__((ext_vector_type(8)));
typedef float    f32x4 __attribute__((ext_vector_type(4)));

// GLU pairing permutation: permuted col c -> source col.
// Within each 32-col group g: positions 0..15 = y0 (src g*16+o), 16..31 = gate (src g*16+(o-16)+256).
__device__ __forceinline__ int glu_perm2(int c) {
    int g = c >> 5, o = c & 31;
    return (o < 16) ? (g * 16 + o) : (g * 16 + (o - 16) + 256);
}

__device__ __forceinline__ void gload16(const void* g, void* l) {
    __builtin_amdgcn_global_load_lds(
        (const __attribute__((address_space(1))) unsigned int*)g,
        (__attribute__((address_space(3))) unsigned int*)l, 16, 0, 0);
}

// ---------------- prep kernels ----------------
__global__ void prep_bn_kernel(
    const float* __restrict__ bn0_g, const float* __restrict__ bn0_b,
    const float* __restrict__ bn0_m, const float* __restrict__ bn0_v,
    const float* __restrict__ ft_g, const float* __restrict__ ft_b,
    const float* __restrict__ ft_m, const float* __restrict__ ft_v,
    const float* __restrict__ att_g, const float* __restrict__ att_b,
    const float* __restrict__ att_m, const float* __restrict__ att_v,
    float* __restrict__ sc0, float* __restrict__ sh0,
    float* __restrict__ ftS, float* __restrict__ ftH,
    float* __restrict__ attS, float* __restrict__ attH)
{
    int idx = blockIdx.x * blockDim.x + threadIdx.x;
    if (idx < 512) {
        float s = bn0_g[idx] * rsqrtf(bn0_v[idx] + EPS_BN);
        sc0[idx] = s;
        sh0[idx] = bn0_b[idx] - bn0_m[idx] * s;
    } else if (idx < 512 + 24 * 512) {
        int q = idx - 512;
        int tb = q >> 9;
        int c = q & 511;
        int src = tb * 512 + glu_perm2(c);
        float s = ft_g[src] * rsqrtf(ft_v[src] + EPS_BN);
        ftS[q] = s;
        ftH[q] = ft_b[src] - ft_m[src] * s;
    } else if (idx < 512 + 24 * 512 + 5 * 512) {
        int q = idx - 512 - 24 * 512;
        float s = att_g[q] * rsqrtf(att_v[q] + EPS_BN);
        attS[q] = s;
        attH[q] = att_b[q] - att_m[q] * s;
    }
}

// Weight prep (batched over grid.y): src [K][512] fp32 -> dst [512][K] f16 (transposed), optional GLU col-perm
__global__ void wprep_kernel(const float* __restrict__ src,
                             f16* __restrict__ dst, int K, int doperm)
{
    const int mat = blockIdx.y;
    src += (size_t)mat * K * 512;
    dst += (size_t)mat * 512 * K;
    int i = blockIdx.x * blockDim.x + threadIdx.x;
    if (i >= 512 * K) return;
    int n = i / K, k = i - n * K;
    int sn = doperm ? glu_perm2(n) : n;
    dst[i] = (f16)src[(size_t)k * 512 + sn];
}

// feats = bn0(features) -> f16; prior = 1 (f16)
__global__ void bn0_split_kernel(const float* __restrict__ x,
                                 const float* __restrict__ sc,
                                 const float* __restrict__ sh,
                                 f16* __restrict__ fh,
                                 f16* __restrict__ prior)
{
    int i = blockIdx.x * blockDim.x + threadIdx.x;   // over B*512/4
    int base = i * 4;
    int c = base & 511;
    float4 xv = *(const float4*)(x + base);
    f16x4 hv;
    hv.x = (f16)(xv.x * sc[c]     + sh[c]);
    hv.y = (f16)(xv.y * sc[c + 1] + sh[c + 1]);
    hv.z = (f16)(xv.z * sc[c + 2] + sh[c + 2]);
    hv.w = (f16)(xv.w * sc[c + 3] + sh[c + 3]);
    *(f16x4*)(fh + base) = hv;
    *(f16x4*)(prior + base) = f16x4{(f16)1.f, (f16)1.f, (f16)1.f, (f16)1.f};
}

__global__ void zero_kernel(float4* __restrict__ p, int n4)
{
    int i = blockIdx.x * blockDim.x + threadIdx.x;
    if (i < n4) p[i] = make_float4(0.f, 0.f, 0.f, 0.f);
}

// ---------------- fp16 MFMA GEMM, 3-buffer counted-vmcnt pipeline ----------------
// Tile 128x128, BK=32, 4 waves (2x2). 3 x 16KB LDS buffers staged via global_load_lds.
// Per iter: s_waitcnt vmcnt(4) (stage t done, t+1 in flight) -> s_barrier ->
// issue stage t+2 -> ds_read + 16 MFMA. Never drains vmcnt(0) inside the loop.
// MODE 0: out = glu(bn(A@W)); MODE 1: + res*sqrt(.5); MODE 2: MODE1 + oacc += relu (oc<128)
template<int MODE>
__global__ __launch_bounds__(256, 3) void gemm_mfma(
    const f16* __restrict__ A, int ldA, int K,
    const f16* __restrict__ B,               // [512][K] f16, GLU-permuted rows
    const float* __restrict__ scale, const float* __restrict__ shift,
    const f16* __restrict__ res,
    f16* __restrict__ out,
    float* __restrict__ oacc)
{
    __shared__ __align__(16) char smem[49152];   // 3 x 16KB
    const int tid  = threadIdx.x;
    const int lane = tid & 63;
    const int w    = tid >> 6;
    const int wm   = w >> 1, wn = w & 1;
    // XCD swizzle: row-panel's 4 col-blocks adjacent on one XCD
    const int d    = blockIdx.x;
    const int by   = (d & 7) + 8 * (d >> 5);
    const int bx   = (d >> 3) & 3;
    const int brow = by * 128;
    const int bcol = bx * 128;
    const int lr   = lane & 15;
    const int lk8  = (lane >> 4) * 8;

    // wave w stages A chunks {2w,2w+1} (16 rows x 32k each) and same B chunks
    const int c0 = 2 * w, c1 = 2 * w + 1;
    const char* gA0 = (const char*)(A + (size_t)(brow + c0 * 16 + lr) * ldA + lk8);
    const char* gA1 = (const char*)(A + (size_t)(brow + c1 * 16 + lr) * ldA + lk8);
    const char* gB0 = (const char*)(B + (size_t)(bcol + c0 * 16 + lr) * K + lk8);
    const char* gB1 = (const char*)(B + (size_t)(bcol + c1 * 16 + lr) * K + lk8);
    const int lA0 = c0 * 1024, lA1 = c1 * 1024;
    const int lB0 = 8192 + c0 * 1024, lB1 = 8192 + c1 * 1024;

    f32x4 acc[4][4];
    #pragma unroll
    for (int m = 0; m < 4; ++m)
        #pragma unroll
        for (int n = 0; n < 4; ++n)
            acc[m][n] = f32x4{0.f, 0.f, 0.f, 0.f};

    const int NT = K >> 5;      // 8 or 16

    // stage s into buffer offset bufo (s indexes K-step; 64 bytes per step)
    auto STAGE = [&](int s, int bufo) {
        const int ko = s * 64;
        gload16(gA0 + ko, smem + bufo + lA0);
        gload16(gA1 + ko, smem + bufo + lA1);
        gload16(gB0 + ko, smem + bufo + lB0);
        gload16(gB1 + ko, smem + bufo + lB1);
    };

    STAGE(0, 0);
    STAGE(1, 16384);

    for (int t = 0; t < NT; ++t) {
        if (t + 1 < NT) asm volatile("s_waitcnt vmcnt(4)" ::: "memory");
        else            asm volatile("s_waitcnt vmcnt(0)" ::: "memory");
        __builtin_amdgcn_s_barrier();
        asm volatile("" ::: "memory");           // pin ds_reads below barrier
        if (t + 2 < NT) STAGE(t + 2, ((t + 2) % 3) * 16384);
        const char* L = smem + (t % 3) * 16384;
        f16x8 a[4];
        #pragma unroll
        for (int m = 0; m < 4; ++m)
            a[m] = *(const f16x8*)(L + (wm * 4 + m) * 1024 + lane * 16);
        #pragma unroll
        for (int n = 0; n < 4; ++n) {
            f16x8 b = *(const f16x8*)(L + 8192 + (wn * 4 + n) * 1024 + lane * 16);
            #pragma unroll
            for (int m = 0; m < 4; ++m)
                acc[m][n] = __builtin_amdgcn_mfma_f32_16x16x32_f16(a[m], b, acc[m][n], 0, 0, 0);
        }
    }

    // epilogue: fragment row' = (lane>>4)*4+r, col' = lane&15; GLU pairs in-lane via permuted W
    #pragma unroll
    for (int p = 0; p < 2; ++p) {
        const int cb = bcol + wn * 64 + p * 32;
        const float sA = scale[cb + lr],      hA = shift[cb + lr];
        const float sB = scale[cb + 16 + lr], hB = shift[cb + 16 + lr];
        const int oc = (cb >> 1) + lr;
        #pragma unroll
        for (int m = 0; m < 4; ++m) {
            const int row0 = brow + wm * 64 + m * 16 + (lane >> 4) * 4;
            #pragma unroll
            for (int r = 0; r < 4; ++r) {
                const int row = row0 + r;
                float y0 = acc[m][2 * p][r]     * sA + hA;
                float y1 = acc[m][2 * p + 1][r] * sB + hB;
                float val = y0 / (1.f + expf(-y1));
                const size_t oi = (size_t)row * 256 + oc;
                if constexpr (MODE >= 1)
                    val += SQRT_HALF * (float)res[oi];
                out[oi] = (f16)val;
                if constexpr (MODE == 2) {
                    if (oc < 128) oacc[(size_t)row * 128 + oc] += fmaxf(val, 0.f);
                }
            }
        }
    }
}

// ---------------- fused attention GEMM + sparsemax (Newton) + mf emission ----------------
// Block: 32 rows x 512 cols, 4 waves. GEMM direct-load (K=128), bn'd att -> LDS f32.
// Phase 2: z = att*prior; Newton solve tau; write mask (d_out), prior *= (1.5-mask) [f16],
// mf = mask*feats (f16) for the next transformer's G1.
__global__ __launch_bounds__(256, 2) void att_sparsemax_kernel(
    const f16* __restrict__ A, int ldA,      // x[:,128:256]
    const f16* __restrict__ Bw,              // [512][128] f16
    const float* __restrict__ scale, const float* __restrict__ shift,
    const f16* __restrict__ feats,
    f16* __restrict__ prior,
    float* __restrict__ mask_out,
    f16* __restrict__ mf)
{
    __shared__ float attLds[32 * 512];
    const int tid  = threadIdx.x;
    const int lane = tid & 63;
    const int w    = tid >> 6;
    const int brow = blockIdx.x * 32;
    const int lr   = lane & 15;
    const int lk   = (lane >> 4) * 8;

    // GEMM: wave w computes cols w*128..+127 for all 32 rows; K=128, NT=4
    f32x4 acc[2][8];
    #pragma unroll
    for (int m = 0; m < 2; ++m)
        #pragma unroll
        for (int n = 0; n < 8; ++n)
            acc[m][n] = f32x4{0.f, 0.f, 0.f, 0.f};

    const f16* pa = A + (size_t)(brow + lr) * ldA + lk;
    const f16* pb = Bw + (size_t)(w * 128 + lr) * 128 + lk;

    f16x8 a0[2], b0[8], a1[2], b1[8];
    #pragma unroll
    for (int m = 0; m < 2; ++m) a0[m] = *(const f16x8*)(pa + m * 16 * ldA);
    #pragma unroll
    for (int n = 0; n < 8; ++n) b0[n] = *(const f16x8*)(pb + n * 16 * 128);

    #pragma unroll
    for (int t = 0; t < 4; t += 2) {
        #pragma unroll
        for (int m = 0; m < 2; ++m) a1[m] = *(const f16x8*)(pa + m * 16 * ldA + (t + 1) * 32);
        #pragma unroll
        for (int n = 0; n < 8; ++n) b1[n] = *(const f16x8*)(pb + n * 16 * 128 + (t + 1) * 32);
        #pragma unroll
        for (int n = 0; n < 8; ++n)
            #pragma unroll
            for (int m = 0; m < 2; ++m)
                acc[m][n] = __builtin_amdgcn_mfma_f32_16x16x32_f16(a0[m], b0[n], acc[m][n], 0, 0, 0);
        if (t + 2 < 4) {
            #pragma unroll
            for (int m = 0; m < 2; ++m) a0[m] = *(const f16x8*)(pa + m * 16 * ldA + (t + 2) * 32);
            #pragma unroll
            for (int n = 0; n < 8; ++n) b0[n] = *(const f16x8*)(pb + n * 16 * 128 + (t + 2) * 32);
        }
        #pragma unroll
        for (int n = 0; n < 8; ++n)
            #pragma unroll
            for (int m = 0; m < 2; ++m)
                acc[m][n] = __builtin_amdgcn_mfma_f32_16x16x32_f16(a1[m], b1[n], acc[m][n], 0, 0, 0);
    }

    // bn'd att -> LDS
    #pragma unroll
    for (int m = 0; m < 2; ++m) {
        const int r0 = m * 16 + (lane >> 4) * 4;
        #pragma unroll
        for (int n = 0; n < 8; ++n) {
            const int col = w * 128 + n * 16 + lr;
            const float s = scale[col], h = shift[col];
            #pragma unroll
            for (int r = 0; r < 4; ++r)
                attLds[(r0 + r) * 512 + col] = acc[m][n][r] * s + h;
        }
    }
    __syncthreads();

    // phase 2: wave w handles rows w*8 .. w*8+7
    for (int rr = 0; rr < 8; ++rr) {
        const int row = w * 8 + rr;
        const int grow = brow + row;
        const size_t gbase = (size_t)grow * 512 + lane;

        float z[8], pr[8];
        #pragma unroll
        for (int j = 0; j < 8; ++j) {
            pr[j] = (float)prior[gbase + j * 64];
            z[j] = attLds[row * 512 + lane + j * 64] * pr[j];
        }
        float mx = z[0];
        #pragma unroll
        for (int j = 1; j < 8; ++j) mx = fmaxf(mx, z[j]);
        #pragma unroll
        for (int off = 32; off; off >>= 1) mx = fmaxf(mx, __shfl_xor(mx, off));

        // Newton on f(tau) = sum(z-tau)+ - 1: convex piecewise-linear, start below root
        float tau = mx - 1.0f;
        for (int it = 0; it < 20; ++it) {
            float s = 0.f, c = 0.f;
            #pragma unroll
            for (int j = 0; j < 8; ++j) {
                float dz = z[j] - tau;
                if (dz > 0.f) { s += dz; c += 1.f; }
            }
            #pragma unroll
            for (int off = 32; off; off >>= 1) {
                s += __shfl_xor(s, off);
                c += __shfl_xor(c, off);
            }
            float tn = tau + (s - 1.0f) / c;
            if (!(tn > tau)) break;    // wave-uniform convergence
            tau = tn;
        }

        #pragma unroll
        for (int j = 0; j < 8; ++j) {
            const size_t ix = gbase + j * 64;
            float m = fmaxf(z[j] - tau, 0.f);
            mask_out[ix] = m;
            prior[ix] = (f16)(pr[j] * (RELAX_C - m));
            mf[ix] = (f16)(m * (float)feats[ix]);
        }
    }
}

// ---------------- final fp32 SIMT GEMM (K=128, N=128) ----------------
__global__ __launch_bounds__(256) void gemm_f32_final(
    const float* __restrict__ A,
    const float* __restrict__ W,
    const float* __restrict__ bias,
    float* __restrict__ out)
{
    __shared__ float As[16][128];
    __shared__ float Bs[16][128];
    const int tid = threadIdx.x;
    const int tm = tid >> 4, tn = tid & 15;
    const int brow = blockIdx.x * 128;
    float acc[8][8] = {};
    for (int k0 = 0; k0 < 128; k0 += 16) {
        #pragma unroll
        for (int i = 0; i < 2; ++i) {
            int f = tid + i * 256;
            int row = f >> 2, kq = (f & 3) << 2;
            float4 av = *(const float4*)(A + (size_t)(brow + row) * 128 + k0 + kq);
            As[kq + 0][row] = av.x;
            As[kq + 1][row] = av.y;
            As[kq + 2][row] = av.z;
            As[kq + 3][row] = av.w;
            int kr = f >> 5, nq = (f & 31) << 2;
            *(float4*)(&Bs[kr][nq]) = *(const float4*)(W + (size_t)(k0 + kr) * 128 + nq);
        }
        __syncthreads();
        #pragma unroll
        for (int kk = 0; kk < 16; ++kk) {
            float a[8], b[8];
            *(float4*)(a)     = *(const float4*)(&As[kk][tm * 8]);
            *(float4*)(a + 4) = *(const float4*)(&As[kk][tm * 8 + 4]);
            *(float4*)(b)     = *(const float4*)(&Bs[kk][tn * 8]);
            *(float4*)(b + 4) = *(const float4*)(&Bs[kk][tn * 8 + 4]);
            #pragma unroll
            for (int i = 0; i < 8; ++i)
                #pragma unroll
                for (int j = 0; j < 8; ++j)
                    acc[i][j] += a[i] * b[j];
        }
        __syncthreads();
    }
    #pragma unroll
    for (int i = 0; i < 8; ++i) {
        int row = brow + tm * 8 + i;
        #pragma unroll
        for (int j = 0; j < 8; ++j)
            out[(size_t)row * 128 + tn * 8 + j] = acc[i][j] + bias[tn * 8 + j];
    }
}

// ---------------- launch ----------------
extern "C" void kernel_launch(void* const* d_in, const int* in_sizes, int n_in,
                              void* d_out, int out_size, void* d_ws, size_t ws_size,
                              hipStream_t stream)
{
    const float* features = (const float*)d_in[0];
    const float* bn0_g = (const float*)d_in[1];
    const float* bn0_b = (const float*)d_in[2];
    const float* bn0_m = (const float*)d_in[3];
    const float* bn0_v = (const float*)d_in[4];
    const float* Ws0   = (const float*)d_in[5];
    const float* Ws1   = (const float*)d_in[6];
    const float* Wu    = (const float*)d_in[7];
    const float* ft_g  = (const float*)d_in[8];
    const float* ft_b  = (const float*)d_in[9];
    const float* ft_m  = (const float*)d_in[10];
    const float* ft_v  = (const float*)d_in[11];
    const float* W_att = (const float*)d_in[12];
    const float* att_g = (const float*)d_in[13];
    const float* att_b = (const float*)d_in[14];
    const float* att_m = (const float*)d_in[15];
    const float* att_v = (const float*)d_in[16];
    const float* Wf    = (const float*)d_in[17];
    const float* bf    = (const float*)d_in[18];
    float* out = (float*)d_out;

    // ---- ws layout (bytes) ----
    char* wp = (char*)d_ws;
    auto alloc = [&](size_t bytes) { char* r = wp; wp += (bytes + 255) & ~(size_t)255; return r; };
    const size_t BR = B_ROWS;
    f16* feats  = (f16*)alloc(BR * 512 * 2);
    f16* mfbuf  = (f16*)alloc(BR * 512 * 2);
    f16* ubuf   = (f16*)alloc(BR * 256 * 2);
    f16* vbuf   = (f16*)alloc(BR * 256 * 2);
    f16* prior  = (f16*)alloc(BR * 512 * 2);
    float* oacc  = (float*)alloc(BR * 128 * 4);
    f16* ws0  = (f16*)alloc(512 * 512 * 2);
    f16* ws1  = (f16*)alloc(512 * 256 * 2);
    f16* wu   = (f16*)alloc((size_t)12 * 512 * 256 * 2);
    f16* wat  = (f16*)alloc((size_t)5 * 512 * 128 * 2);
    float* ftS  = (float*)alloc(24 * 512 * 4);
    float* ftH  = (float*)alloc(24 * 512 * 4);
    float* attS = (float*)alloc(5 * 512 * 4);
    float* attH = (float*)alloc(5 * 512 * 4);
    float* sc0  = (float*)alloc(512 * 4);
    float* sh0  = (float*)alloc(512 * 4);

    // ---- prep ----
    prep_bn_kernel<<<60, 256, 0, stream>>>(
        bn0_g, bn0_b, bn0_m, bn0_v, ft_g, ft_b, ft_m, ft_v,
        att_g, att_b, att_m, att_v, sc0, sh0, ftS, ftH, attS, attH);
    wprep_kernel<<<dim3(512 * 512 / 256, 1), 256, 0, stream>>>(Ws0, ws0, 512, 1);
    wprep_kernel<<<dim3(512 * 256 / 256, 1), 256, 0, stream>>>(Ws1, ws1, 256, 1);
    wprep_kernel<<<dim3(512 * 256 / 256, 12), 256, 0, stream>>>(Wu, wu, 256, 1);
    wprep_kernel<<<dim3(512 * 128 / 256, 5), 256, 0, stream>>>(W_att, wat, 128, 0);
    bn0_split_kernel<<<(B_ROWS * 512 / 4) / 256, 256, 0, stream>>>(
        features, sc0, sh0, feats, prior);
    zero_kernel<<<(B_ROWS * 128 / 4) / 256, 256, 0, stream>>>((float4*)oacc, B_ROWS * 128 / 4);

    const int grid = 4 * (B_ROWS / 128);   // 1024 blocks, swizzled in-kernel

    // transformer t: G1 (K=512) + G2..G4 (K=256)
    auto ft = [&](const f16* in, int t, bool accum) {
        const f16* wu0 = wu + (size_t)(t * 2 + 0) * 131072;
        const f16* wu1 = wu + (size_t)(t * 2 + 1) * 131072;
        gemm_mfma<0><<<grid, 256, 0, stream>>>(in, 512, 512, ws0,
            ftS + (t * 4 + 0) * 512, ftH + (t * 4 + 0) * 512,
            nullptr, ubuf, nullptr);
        gemm_mfma<1><<<grid, 256, 0, stream>>>(ubuf, 256, 256, ws1,
            ftS + (t * 4 + 1) * 512, ftH + (t * 4 + 1) * 512,
            ubuf, vbuf, nullptr);
        gemm_mfma<1><<<grid, 256, 0, stream>>>(vbuf, 256, 256, wu0,
            ftS + (t * 4 + 2) * 512, ftH + (t * 4 + 2) * 512,
            vbuf, ubuf, nullptr);
        if (accum)
            gemm_mfma<2><<<grid, 256, 0, stream>>>(ubuf, 256, 256, wu1,
                ftS + (t * 4 + 3) * 512, ftH + (t * 4 + 3) * 512,
                ubuf, vbuf, oacc);
        else
            gemm_mfma<1><<<grid, 256, 0, stream>>>(ubuf, 256, 256, wu1,
                ftS + (t * 4 + 3) * 512, ftH + (t * 4 + 3) * 512,
                ubuf, vbuf, nullptr);
    };

    ft(feats, 0, false);

    for (int s = 0; s < NSTEPS; ++s) {
        float* mask_s = out + 4194304 + (size_t)s * 16777216;
        att_sparsemax_kernel<<<B_ROWS / 32, 256, 0, stream>>>(
            vbuf + 128, 256, wat + (size_t)s * 65536,
            attS + s * 512, attH + s * 512,
            feats, prior, mask_s, mfbuf);
        ft(mfbuf, s + 1, true);
    }

    gemm_f32_final<<<B_ROWS / 128, 256, 0, stream>>>(oacc, Wf, bf, out);
}